// Round 1
// baseline (3381.928 us; speedup 1.0000x reference)
//
#include <hip/hip_runtime.h>
#include <hip/hip_bf16.h>
#include <math.h>

// Gate kernel: logits = x @ W^T ; scores = sigmoid(logits) + bias ; top-8 ; normalize *2.5
// T = 16384, H = K = 4096, E = 256.

constexpr int E_EXPERTS = 256;
constexpr int KDIM      = 4096;
constexpr int BM = 64, BN = 128, BK = 32, NTHREADS = 256;
constexpr int TOPK = 8;
constexpr float SCALE = 2.5f;

// ---- async global->LDS helper (16B per lane, wave-uniform LDS base) ----
__device__ __forceinline__ void load_lds16(const float* g, float* l) {
    auto gp = (const __attribute__((address_space(1))) float*)g;
    auto lp = (__attribute__((address_space(3))) float*)(uintptr_t)l;
    __builtin_amdgcn_global_load_lds(gp, lp, 16, 0, 0);
}

// LDS layout per buffer: A [64][32] f32 (2048 floats), then B [128][32] f32 swizzled (4096 floats).
// B swizzle (float-level): logical B[row][kk] stored at float offset row*32 + (kk ^ ((row&7)<<2)).
__global__ __launch_bounds__(NTHREADS, 3) void gate_gemm(
    const float* __restrict__ X, const float* __restrict__ W,
    const float* __restrict__ Bias, float* __restrict__ S, int T) {
    __shared__ float lds[2 * (BM * BK + BN * BK)];  // 2 * 6144 floats = 48 KiB

    const int tid  = threadIdx.x;
    const int wave = tid >> 6;
    const int lane = tid & 63;
    const int r    = tid >> 5;   // 0..7  : row group (rows r*8 .. r*8+7)
    const int c    = tid & 31;   // 0..31 : col lane  (cols c + 32*j)

    const int tok0 = blockIdx.x * BM;
    const int e0   = blockIdx.y * BN;

    float acc[8][4];
#pragma unroll
    for (int i = 0; i < 8; ++i)
#pragma unroll
        for (int j = 0; j < 4; ++j) acc[i][j] = 0.0f;

    auto stage = [&](int buf, int k0) {
        float* base = lds + buf * 6144;
        // A tile: 64x32 floats = 8 KiB = 2 issues x (4 waves x 1 KiB)
#pragma unroll
        for (int i = 0; i < 2; ++i) {
            int f   = i * 1024 + wave * 256 + lane * 4;  // linear float offset in A region
            int row = f >> 5, col = f & 31;
            load_lds16(X + (size_t)(tok0 + row) * KDIM + k0 + col,
                       base + i * 1024 + wave * 256);    // wave-uniform LDS base
        }
        // B tile: 128x32 floats = 16 KiB = 4 issues; pre-swizzled global source
#pragma unroll
        for (int i = 0; i < 4; ++i) {
            int f      = i * 1024 + wave * 256 + lane * 4;
            int row    = f >> 5, q = f & 31;
            int srcCol = q ^ ((row & 7) << 2);           // inverse swizzle on the source
            load_lds16(W + (size_t)(e0 + row) * KDIM + k0 + srcCol,
                       base + 2048 + i * 1024 + wave * 256);
        }
    };

    auto compute = [&](int buf) {
        const float* As = lds + buf * 6144;
        const float* Bs = As + 2048;
#pragma unroll
        for (int kk0 = 0; kk0 < BK; kk0 += 4) {
            float4 a[8], b[4];
#pragma unroll
            for (int i = 0; i < 8; ++i)
                a[i] = *(const float4*)(As + (r * 8 + i) * BK + kk0);
#pragma unroll
            for (int j = 0; j < 4; ++j) {
                int row = c + 32 * j;
                b[j] = *(const float4*)(Bs + row * BK + (kk0 ^ ((row & 7) << 2)));
            }
#pragma unroll
            for (int i = 0; i < 8; ++i)
#pragma unroll
                for (int j = 0; j < 4; ++j) {
                    float p = a[i].x * b[j].x;
                    p = fmaf(a[i].y, b[j].y, p);
                    p = fmaf(a[i].z, b[j].z, p);
                    p = fmaf(a[i].w, b[j].w, p);
                    acc[i][j] += p;
                }
        }
    };

    stage(0, 0);
    int buf = 0;
    constexpr int NSTEPS = KDIM / BK;  // 128
    for (int ks = 0; ks < NSTEPS; ++ks) {
        __syncthreads();                       // drains vmcnt -> staged buf ready
        if (ks + 1 < NSTEPS) stage(buf ^ 1, (ks + 1) * BK);
        compute(buf);
        __syncthreads();                       // all waves done reading buf
        buf ^= 1;
    }

    // Epilogue: sigmoid + bias, store scores
#pragma unroll
    for (int j = 0; j < 4; ++j) {
        int col = e0 + c + 32 * j;
        float bv = Bias[col];
#pragma unroll
        for (int i = 0; i < 8; ++i) {
            int row = tok0 + r * 8 + i;
            float v = acc[i][j];
            float sc = 1.0f / (1.0f + expf(-v)) + bv;
            S[(size_t)row * E_EXPERTS + col] = sc;
        }
    }
}

// One wave per token: 256 scores, 4/lane; 8 rounds of butterfly argmax.
// Tie-break: higher value wins; equal value -> lower index wins (matches lax.top_k / np).
__global__ __launch_bounds__(256) void gate_topk(
    const float* __restrict__ S, float* __restrict__ outIdx,
    float* __restrict__ outW, int T) {
    const int wave = threadIdx.x >> 6;
    const int lane = threadIdx.x & 63;
    const int t    = blockIdx.x * 4 + wave;
    if (t >= T) return;

    const float* row = S + (size_t)t * E_EXPERTS;
    float v[4];
    int   idx[4];
#pragma unroll
    for (int j = 0; j < 4; ++j) {
        idx[j] = lane + 64 * j;
        v[j]   = row[idx[j]];
    }

    float tv[8];
    int   ti[8];
#pragma unroll
    for (int k = 0; k < TOPK; ++k) {
        float bv = v[0];
        int   bi = idx[0];
#pragma unroll
        for (int j = 1; j < 4; ++j)
            if (v[j] > bv) { bv = v[j]; bi = idx[j]; }   // strict >: lower idx kept on ties
#pragma unroll
        for (int off = 1; off < 64; off <<= 1) {
            float ov = __shfl_xor(bv, off);
            int   oi = __shfl_xor(bi, off);
            if (ov > bv || (ov == bv && oi < bi)) { bv = ov; bi = oi; }
        }
        tv[k] = bv;
        ti[k] = bi;
#pragma unroll
        for (int j = 0; j < 4; ++j)
            if (idx[j] == bi) v[j] = -INFINITY;
    }

    float denom = 0.0f;
#pragma unroll
    for (int k = 0; k < TOPK; ++k) denom += tv[k];
    denom += 1e-20f;

#pragma unroll
    for (int k = 0; k < TOPK; ++k) {
        if (lane == k) {
            outIdx[(size_t)t * TOPK + k] = (float)ti[k];
            outW[(size_t)t * TOPK + k]   = (tv[k] / denom) * SCALE;
        }
    }
}

extern "C" void kernel_launch(void* const* d_in, const int* in_sizes, int n_in,
                              void* d_out, int out_size, void* d_ws, size_t ws_size,
                              hipStream_t stream) {
    const float* x    = (const float*)d_in[0];
    const float* w    = (const float*)d_in[1];
    const float* bias = (const float*)d_in[2];

    const int T = in_sizes[0] / KDIM;  // 16384

    float* S      = (float*)d_ws;                    // [T][256] scores, 16 MiB
    float* outIdx = (float*)d_out;                   // idx chunk (as float values)
    float* outW   = outIdx + (size_t)T * TOPK;       // weight chunk

    dim3 grid(T / BM, E_EXPERTS / BN);               // 256 x 2
    gate_gemm<<<grid, NTHREADS, 0, stream>>>(x, w, bias, S, T);
    gate_topk<<<T / 4, 256, 0, stream>>>(S, outIdx, outW, T);
}

// Round 2
// 204.049 us; speedup vs baseline: 16.5741x; 16.5741x over previous
//
#include <hip/hip_runtime.h>
#include <hip/hip_bf16.h>
#include <math.h>

// Gate: logits = x @ W^T ; scores = sigmoid(logits) + bias ; top-8 ; normalize *2.5
// T=16384, H=K=4096, E=256.
// fp32 GEMM emulated via EXACT 3-way bf16 truncation split (x = h1+h2+h3 bit-exact),
// keeping 6 cross products -> error ~2^-25, accumulated by bf16 MFMA into fp32.

using bf16x8  = __attribute__((ext_vector_type(8))) short;
using f32x4   = __attribute__((ext_vector_type(4))) float;
using short4v = __attribute__((ext_vector_type(4))) short;

constexpr int E_EXPERTS = 256;
constexpr int KDIM      = 4096;
constexpr int TOPK      = 8;
constexpr float SCALE   = 2.5f;

constexpr int BM = 64, BN = 128, BK = 64, NT = 256;
constexpr int NSTEP = KDIM / BK;   // 64

__device__ __forceinline__ void load_lds16(const short* g, short* l) {
    auto gp = (const __attribute__((address_space(1))) short*)g;
    auto lp = (__attribute__((address_space(3))) short*)(uintptr_t)l;
    __builtin_amdgcn_global_load_lds(gp, lp, 16, 0, 0);
}

// Exact truncation split: x == bf16(h1)+bf16(h2)+bf16(h3) bit-exactly (normal fp32).
__device__ __forceinline__ void split1(float x, short& h1, short& h2, short& h3) {
    unsigned u = __float_as_uint(x);
    h1 = (short)(u >> 16);
    float r1 = x - __uint_as_float(u & 0xFFFF0000u);
    unsigned u1 = __float_as_uint(r1);
    h2 = (short)(u1 >> 16);
    float r2 = r1 - __uint_as_float(u1 & 0xFFFF0000u);
    h3 = (short)(__float_as_uint(r2) >> 16);
}

__global__ void wsplit_kernel(const float* __restrict__ W, short* __restrict__ W1,
                              short* __restrict__ W2, short* __restrict__ W3) {
    int i = blockIdx.x * 256 + threadIdx.x;   // float4 index
    float4 w = ((const float4*)W)[i];
    short4v s1, s2, s3;
    short a, b, c;
    split1(w.x, a, b, c); s1.x = a; s2.x = b; s3.x = c;
    split1(w.y, a, b, c); s1.y = a; s2.y = b; s3.y = c;
    split1(w.z, a, b, c); s1.z = a; s2.z = b; s3.z = c;
    split1(w.w, a, b, c); s1.w = a; s2.w = b; s3.w = c;
    ((short4v*)W1)[i] = s1;
    ((short4v*)W2)[i] = s2;
    ((short4v*)W3)[i] = s3;
}

// LDS (shorts): A levels at lev*4096 ([64 rows][64]), B levels at 12288+lev*8192
// ([128 rows][64]). Rows are 128 B; 16-B slot s of row r holds logical k-group
// s ^ (r&7)  (XOR swizzle -> 2-way bank access on ds_read_b128 = free).
__global__ __launch_bounds__(NT, 2) void gate_gemm(
    const float* __restrict__ X,
    const short* __restrict__ W1, const short* __restrict__ W2, const short* __restrict__ W3,
    const float* __restrict__ Bias, float* __restrict__ S) {
    __shared__ short lds[36864];   // 72 KiB

    const int tid  = threadIdx.x;
    const int lane = tid & 63;
    const int wave = tid >> 6;
    const int wm   = wave >> 1;    // 0..1 : 32-token half
    const int wn   = wave & 1;     // 0..1 : 64-expert half

    // Bijective XCD swizzle: each XCD gets 64 consecutive logical ids; the two
    // expert-halves (by) of a token tile land on the same XCD -> X L2-reuse.
    const int p       = blockIdx.x;
    const int cpx     = gridDim.x >> 3;            // 64
    const int logical = (p & 7) * cpx + (p >> 3);
    const int tok0 = (logical >> 1) * BM;
    const int e0   = (logical & 1) * BN;

    // A staging: thread owns 16-B slots (t) and (256+t) -> rows t>>3 and 32+(t>>3),
    // swizzled k-group g = (t&7) ^ (row&7) (same for both rows; 32 apart).
    const int ar0 = tid >> 3;                       // 0..31
    const int ag  = (tid & 7) ^ (ar0 & 7);
    const float* xr0 = X + (size_t)(tok0 + ar0) * KDIM + ag * 8;
    const float* xr1 = xr0 + (size_t)32 * KDIM;

    // B staging: per (lev,h) issue: e = h*32 + wave*8 + (lane>>3); e&7 == lane>>3;
    // pre-swizzled source slot = (lane&7) ^ (lane>>3).
    const int bsl = (lane & 7) ^ (lane >> 3);

    f32x4 acc[2][4];
#pragma unroll
    for (int i = 0; i < 2; ++i)
#pragma unroll
        for (int j = 0; j < 4; ++j) acc[i][j] = f32x4{0.f, 0.f, 0.f, 0.f};

    for (int ks = 0; ks < NSTEP; ++ks) {
        const int k0 = ks * BK;

        // ---- stage: issue global loads first (A fp32 regs + B direct-to-LDS)
        float4 a0 = *(const float4*)(xr0 + k0);
        float4 a1 = *(const float4*)(xr0 + k0 + 4);
        float4 b0 = *(const float4*)(xr1 + k0);
        float4 b1 = *(const float4*)(xr1 + k0 + 4);

#pragma unroll
        for (int lev = 0; lev < 3; ++lev) {
            const short* wl = (lev == 0) ? W1 : ((lev == 1) ? W2 : W3);
#pragma unroll
            for (int h = 0; h < 4; ++h) {
                const int e = h * 32 + wave * 8 + (lane >> 3);
                load_lds16(wl + (size_t)(e0 + e) * KDIM + k0 + bsl * 8,
                           &lds[12288 + lev * 8192 + h * 2048 + wave * 512]);
            }
        }

        // split A (exact) and write to LDS (linear stride-16B -> conflict-free)
        bf16x8 p1, p2, p3, q1, q2, q3;
        {
            float v[8] = {a0.x, a0.y, a0.z, a0.w, a1.x, a1.y, a1.z, a1.w};
#pragma unroll
            for (int j = 0; j < 8; ++j) {
                short h1, h2, h3; split1(v[j], h1, h2, h3);
                p1[j] = h1; p2[j] = h2; p3[j] = h3;
            }
        }
        {
            float v[8] = {b0.x, b0.y, b0.z, b0.w, b1.x, b1.y, b1.z, b1.w};
#pragma unroll
            for (int j = 0; j < 8; ++j) {
                short h1, h2, h3; split1(v[j], h1, h2, h3);
                q1[j] = h1; q2[j] = h2; q3[j] = h3;
            }
        }
        *(bf16x8*)&lds[0 * 4096 + tid * 8]        = p1;
        *(bf16x8*)&lds[1 * 4096 + tid * 8]        = p2;
        *(bf16x8*)&lds[2 * 4096 + tid * 8]        = p3;
        *(bf16x8*)&lds[0 * 4096 + 2048 + tid * 8] = q1;
        *(bf16x8*)&lds[1 * 4096 + 2048 + tid * 8] = q2;
        *(bf16x8*)&lds[2 * 4096 + 2048 + tid * 8] = q3;

        __syncthreads();   // drains vmcnt (global_load_lds) + lgkmcnt (ds_write)

        // ---- compute: 2 k-subs x (2 mf x 4 nf) x 6 level-products
#pragma unroll
        for (int ksub = 0; ksub < 2; ++ksub) {
            const int slot = (ksub * 4 + (lane >> 4)) ^ (lane & 7);
            bf16x8 af[2][3];
#pragma unroll
            for (int mf = 0; mf < 2; ++mf) {
                const int r = wm * 32 + mf * 16 + (lane & 15);
#pragma unroll
                for (int lev = 0; lev < 3; ++lev)
                    af[mf][lev] = *(const bf16x8*)&lds[lev * 4096 + r * 64 + slot * 8];
            }
            bf16x8 bfr[4][3];
#pragma unroll
            for (int nf = 0; nf < 4; ++nf) {
                const int e = wn * 64 + nf * 16 + (lane & 15);
#pragma unroll
                for (int lev = 0; lev < 3; ++lev)
                    bfr[nf][lev] = *(const bf16x8*)&lds[12288 + lev * 8192 + e * 64 + slot * 8];
            }
#pragma unroll
            for (int mf = 0; mf < 2; ++mf)
#pragma unroll
                for (int nf = 0; nf < 4; ++nf) {
                    f32x4 c = acc[mf][nf];
                    c = __builtin_amdgcn_mfma_f32_16x16x32_bf16(af[mf][0], bfr[nf][0], c, 0, 0, 0);
                    c = __builtin_amdgcn_mfma_f32_16x16x32_bf16(af[mf][0], bfr[nf][1], c, 0, 0, 0);
                    c = __builtin_amdgcn_mfma_f32_16x16x32_bf16(af[mf][1], bfr[nf][0], c, 0, 0, 0);
                    c = __builtin_amdgcn_mfma_f32_16x16x32_bf16(af[mf][1], bfr[nf][1], c, 0, 0, 0);
                    c = __builtin_amdgcn_mfma_f32_16x16x32_bf16(af[mf][0], bfr[nf][2], c, 0, 0, 0);
                    c = __builtin_amdgcn_mfma_f32_16x16x32_bf16(af[mf][2], bfr[nf][0], c, 0, 0, 0);
                    acc[mf][nf] = c;
                }
        }
        __syncthreads();   // all waves done reading before next stage overwrites
    }

    // ---- epilogue: sigmoid + bias -> scores
    // C/D layout (m89-verified): col(expert) = lane&15, row(token) = (lane>>4)*4 + v.
#pragma unroll
    for (int mf = 0; mf < 2; ++mf)
#pragma unroll
        for (int nf = 0; nf < 4; ++nf) {
            const int ec = e0 + wn * 64 + nf * 16 + (lane & 15);
            const float bv = Bias[ec];
#pragma unroll
            for (int v = 0; v < 4; ++v) {
                const int tr = tok0 + wm * 32 + mf * 16 + (lane >> 4) * 4 + v;
                const float logit = acc[mf][nf][v];
                S[(size_t)tr * E_EXPERTS + ec] = 1.0f / (1.0f + expf(-logit)) + bv;
            }
        }
}

// One wave per token: 256 scores, 4/lane; 8 rounds of butterfly argmax.
// Tie-break: higher value wins; equal value -> lower index (matches lax.top_k / np).
__global__ __launch_bounds__(256) void gate_topk(
    const float* __restrict__ S, float* __restrict__ outIdx,
    float* __restrict__ outW, int T) {
    const int wave = threadIdx.x >> 6;
    const int lane = threadIdx.x & 63;
    const int t    = blockIdx.x * 4 + wave;
    if (t >= T) return;

    const float* row = S + (size_t)t * E_EXPERTS;
    float v[4];
    int   idx[4];
#pragma unroll
    for (int j = 0; j < 4; ++j) {
        idx[j] = lane + 64 * j;
        v[j]   = row[idx[j]];
    }

    float tv[8];
    int   ti[8];
#pragma unroll
    for (int k = 0; k < TOPK; ++k) {
        float bv = v[0];
        int   bi = idx[0];
#pragma unroll
        for (int j = 1; j < 4; ++j)
            if (v[j] > bv) { bv = v[j]; bi = idx[j]; }
#pragma unroll
        for (int off = 1; off < 64; off <<= 1) {
            float ov = __shfl_xor(bv, off);
            int   oi = __shfl_xor(bi, off);
            if (ov > bv || (ov == bv && oi < bi)) { bv = ov; bi = oi; }
        }
        tv[k] = bv;
        ti[k] = bi;
#pragma unroll
        for (int j = 0; j < 4; ++j)
            if (idx[j] == bi) v[j] = -INFINITY;
    }

    float denom = 0.0f;
#pragma unroll
    for (int k = 0; k < TOPK; ++k) denom += tv[k];
    denom += 1e-20f;

#pragma unroll
    for (int k = 0; k < TOPK; ++k) {
        if (lane == k) {
            outIdx[(size_t)t * TOPK + k] = (float)ti[k];
            outW[(size_t)t * TOPK + k]   = (tv[k] / denom) * SCALE;
        }
    }
}

extern "C" void kernel_launch(void* const* d_in, const int* in_sizes, int n_in,
                              void* d_out, int out_size, void* d_ws, size_t ws_size,
                              hipStream_t stream) {
    const float* x    = (const float*)d_in[0];
    const float* w    = (const float*)d_in[1];
    const float* bias = (const float*)d_in[2];

    const int T = in_sizes[0] / KDIM;   // 16384

    float* S  = (float*)d_ws;                                        // [T][256] f32, 16 MiB
    short* W1 = (short*)((char*)d_ws + (size_t)T * E_EXPERTS * 4);   // 3 x 2 MiB bf16
    short* W2 = W1 + (size_t)E_EXPERTS * KDIM;
    short* W3 = W2 + (size_t)E_EXPERTS * KDIM;

    float* outIdx = (float*)d_out;                  // idx chunk (as float values)
    float* outW   = outIdx + (size_t)T * TOPK;      // weight chunk

    wsplit_kernel<<<(E_EXPERTS * KDIM / 4) / 256, 256, 0, stream>>>(w, W1, W2, W3);
    gate_gemm<<<(T / BM) * (E_EXPERTS / BN), NT, 0, stream>>>(x, W1, W2, W3, bias, S);
    gate_topk<<<T / 4, 256, 0, stream>>>(S, outIdx, outW, T);
}